// Round 5
// baseline (35.708 us; speedup 1.0000x reference)
//
#include <hip/hip_runtime.h>

// ---- problem constants ----
#define IN_C  16
#define OUT_C 32
#define NB 2
#define TT 8
#define DD 8
#define HH 32
#define WW 32
#define TP 10
#define DP 10
#define HP 34
#define WPAD 34

// xt layout: [n][tp][dp][hp][icblk(2)][w(34)][ic8] bf16 ; row = 2*34*8 elems = 1088 B
#define XT_ROW_B  1088
#define XT_ELEMS  (NB*TP*DP*HP*2*WPAD*8)     // 3,699,200 bf16 = 7,398,400 B
// wt layout: [tap(82)][icblk(2)][oc(32)][ic8] bf16 ; per-tap = 1024 B (tap 81 zeroed)
#define WT_ELEMS  (82*2*OUT_C*8)             // 41,984 bf16

// conv LDS: A slab = 20 rows x 1088 B (18 valid + 2 pad so staging is 5 full
// 256-thread rounds); double-buffered. B = 84 taps x 1024 B staged once.
#define A_SLAB_B 20480
#define B_LDS_B  86016

typedef __bf16 bf16x8 __attribute__((ext_vector_type(8)));
typedef float  f32x4  __attribute__((ext_vector_type(4)));
typedef float  f32x16 __attribute__((ext_vector_type(16)));

__device__ __forceinline__ unsigned short f2bf(float f) {
    unsigned int u = __builtin_bit_cast(unsigned int, f);
    u += 0x7fffu + ((u >> 16) & 1u);       // RNE
    return (unsigned short)(u >> 16);
}

__device__ __forceinline__ void gload16(const void* g, void* l) {
    __builtin_amdgcn_global_load_lds(
        (const __attribute__((address_space(1))) unsigned int*)g,
        (__attribute__((address_space(3))) unsigned int*)l, 16, 0, 0);
}

// ---------------- zero-fill xt ----------------
__global__ __launch_bounds__(256) void fill_zero_kernel(f32x4* __restrict__ p, int n16) {
    int i = blockIdx.x * blockDim.x + threadIdx.x;
    if (i < n16) {
        f32x4 z = {0.f, 0.f, 0.f, 0.f};
        p[i] = z;
    }
}

// ---------------- x -> bf16, padded, layout [n][tp][dp][hp][icblk][w][8] ----------------
__global__ __launch_bounds__(512) void xpose_kernel(const float* __restrict__ x,
                                                    unsigned short* __restrict__ xt) {
    __shared__ unsigned short ls[WW * IN_C];
    int b = blockIdx.x;
    int h = b & 31, d = (b >> 5) & 7, t = (b >> 8) & 7, n = b >> 11;
    int tid = threadIdx.x;
    int c = tid >> 5, w = tid & 31;
    float v = x[((((size_t)(n * IN_C + c) * TT + t) * DD + d) * HH + h) * WW + w];
    ls[w * IN_C + c] = f2bf(v);
    __syncthreads();
    if (tid < 256) {
        int blk = tid >> 7;             // icblk
        int rem = tid & 127;
        int w2 = rem >> 2, cp = rem & 3;
        int c0 = blk * 8 + cp * 2;
        unsigned int val = (unsigned int)ls[w2 * 16 + c0] |
                           ((unsigned int)ls[w2 * 16 + c0 + 1] << 16);
        unsigned char* row = (unsigned char*)xt +
            (size_t)((((n * TP) + t + 1) * DP + d + 1) * HP + h + 1) * XT_ROW_B;
        *(unsigned int*)(row + blk * 544 + (w2 + 1) * 16 + cp * 4) = val;
    }
}

// ---------------- weight -> wt[82][icblk][oc][8] bf16 (tap 81 zeroed) ----------------
__global__ void wxform_kernel(const float* __restrict__ wsrc,
                              unsigned short* __restrict__ wt) {
    int idx = blockIdx.x * blockDim.x + threadIdx.x;
    if (idx >= WT_ELEMS) return;
    int tap = idx >> 9;
    int r = idx & 511;
    int icblk = r >> 8, oc = (r >> 3) & 31, i8 = r & 7;
    int ic = icblk * 8 + i8;
    float v = (tap < 81) ? wsrc[(oc * IN_C + ic) * 81 + tap] : 0.0f;
    wt[idx] = f2bf(v);
}

// ---------------- main: 32x32x16 MFMA implicit GEMM ----------------
// block = 4 waves (256 thr), tile = 16 h-rows x 32 w x 32 oc; wave = 4 h-rows.
// Per (kt,kd) plane per wave: 9 B-frag reads (held in regs) + 18 A reads
// (6 rows x 3 kw) feed 36 MFMAs (one tap each: M=32w, N=32oc, K=16ic).
__global__ __launch_bounds__(256, 1) void conv_main_kernel(const unsigned short* __restrict__ xt,
                                                           const unsigned short* __restrict__ wt,
                                                           const float* __restrict__ bias,
                                                           float* __restrict__ out) {
    __shared__ __align__(16) unsigned char As0[A_SLAB_B];
    __shared__ __align__(16) unsigned char As1[A_SLAB_B];
    __shared__ __align__(16) unsigned char Bs[B_LDS_B];

    // XCD-aware swizzle (256 % 8 == 0 -> bijective)
    int bid = blockIdx.x;
    int lb  = (bid & 7) * 32 + (bid >> 3);
    int hb = lb & 1, d = (lb >> 1) & 7, t = (lb >> 4) & 7, n = lb >> 7;
    int h0 = hb * 16;                  // padded base row of slab
    int tid  = threadIdx.x;
    int wv   = tid >> 6;               // 0..3, owns output rows h0+4wv..+3
    int lane = tid & 63;
    int l31  = lane & 31;
    int kblk = lane >> 5;              // k-chunk (ic 0-7 vs 8-15)

    int ab = kblk * 544 + l31 * 16;    // A-frag lane offset within a row
    int bb = kblk * 512 + l31 * 16;    // B-frag lane offset within a tap

    f32x16 acc[4];
#pragma unroll
    for (int m = 0; m < 4; ++m) acc[m] = {};

    // ---- prologue: stage all B (84 taps) + A plane 0 ----
#pragma unroll
    for (int i = 0; i < 21; ++i)
        gload16((const unsigned char*)wt + (tid + i * 256) * 16, Bs + (tid + i * 256) * 16);
    {
        const unsigned char* src = (const unsigned char*)xt +
            (size_t)(((n * TP + t) * DP + d) * HP + h0) * XT_ROW_B;
#pragma unroll
        for (int i = 0; i < 5; ++i)
            gload16(src + (tid + i * 256) * 16, As0 + (tid + i * 256) * 16);
    }
    asm volatile("s_waitcnt vmcnt(0)" ::: "memory");
    __syncthreads();

    // ---- 9 phases: plane p = (kt,kd), A in buf[p&1], stage p+1 into buf[(p+1)&1] ----
#pragma unroll
    for (int p = 0; p < 9; ++p) {
        const int kt = p / 3, kd = p % 3;
        if (p < 8) {
            const int ktn = (p + 1) / 3, kdn = (p + 1) % 3;
            const unsigned char* src = (const unsigned char*)xt +
                (size_t)(((n * TP + t + ktn) * DP + d + kdn) * HP + h0) * XT_ROW_B;
            unsigned char* dst = (p & 1) ? As0 : As1;
#pragma unroll
            for (int i = 0; i < 5; ++i)
                gload16(src + (tid + i * 256) * 16, dst + (tid + i * 256) * 16);
        }
        const unsigned char* A = (p & 1) ? As1 : As0;

        // B fragments for this plane -> registers
        bf16x8 bf[3][3];
#pragma unroll
        for (int kh = 0; kh < 3; ++kh)
#pragma unroll
            for (int kw = 0; kw < 3; ++kw)
                bf[kh][kw] = *(const bf16x8*)(Bs + ((kt * 27 + kd * 9 + kh * 3 + kw) << 10) + bb);

        // 6 input rows x 3 kw shifts; each A-frag feeds all valid kh taps
#pragma unroll
        for (int r = 0; r < 6; ++r) {
#pragma unroll
            for (int kw = 0; kw < 3; ++kw) {
                bf16x8 a = *(const bf16x8*)(A + (4 * wv + r) * 1088 + ab + kw * 16);
#pragma unroll
                for (int kh = 0; kh < 3; ++kh) {
                    const int m = r - kh;
                    if (m >= 0 && m < 4)
                        acc[m] = __builtin_amdgcn_mfma_f32_32x32x16_bf16(a, bf[kh][kw], acc[m], 0, 0, 0);
                }
            }
        }

        if (p < 8) {
            asm volatile("s_waitcnt vmcnt(0)" ::: "memory");
            __syncthreads();
        }
    }

    // ---- epilogue: C/D layout col(oc)=lane&31, row(w)=(reg&3)+8*(reg>>2)+4*(lane>>5) ----
    float bsv = bias[l31];
#pragma unroll
    for (int m = 0; m < 4; ++m) {
        int oh = h0 + 4 * wv + m;
        float* obase = out + (((((size_t)n * OUT_C + l31) * TT + t) * DD + d) * HH + oh) * WW;
#pragma unroll
        for (int q = 0; q < 4; ++q) {
            f32x4 v = { acc[m][4 * q + 0] + bsv, acc[m][4 * q + 1] + bsv,
                        acc[m][4 * q + 2] + bsv, acc[m][4 * q + 3] + bsv };
            *(f32x4*)(obase + 8 * q + 4 * kblk) = v;
        }
    }
}

extern "C" void kernel_launch(void* const* d_in, const int* in_sizes, int n_in,
                              void* d_out, int out_size, void* d_ws, size_t ws_size,
                              hipStream_t stream) {
    const float* x    = (const float*)d_in[0];
    const float* wsrc = (const float*)d_in[1];
    const float* bias = (const float*)d_in[2];
    float* out        = (float*)d_out;

    unsigned short* xt = (unsigned short*)d_ws;
    unsigned short* wt = xt + XT_ELEMS;

    const int n16 = (XT_ELEMS * 2) / 16;     // 462,400 16B lines
    fill_zero_kernel<<<(n16 + 255) / 256, 256, 0, stream>>>((f32x4*)d_ws, n16);

    xpose_kernel<<<NB * TT * DD * HH, 512, 0, stream>>>(x, xt);
    wxform_kernel<<<WT_ELEMS / 256, 256, 0, stream>>>(wsrc, wt);
    conv_main_kernel<<<NB * TT * DD * 2, 256, 0, stream>>>(xt, wt, bias, out);
}

// Round 6
// 27.490 us; speedup vs baseline: 1.2990x; 1.2990x over previous
//
#include <hip/hip_runtime.h>

// ---- problem constants ----
#define IN_C  16
#define OUT_C 32
#define NB 2
#define TT 8
#define DD 8
#define HH 32
#define WW 32
#define TP 10
#define DP 10
#define HP 34
#define WPAD 34

// xt layout: [n][tp][dp][hp][icblk(2)][w(34)][ic8] bf16 ; row = 1088 B
#define XT_ROW_B  1088
#define XT_ELEMS  (NB*TP*DP*HP*2*WPAD*8)     // 3,699,200 bf16 = 7,398,400 B
// wt layout: [tap(84 padded)][icblk(2)][oc(32)][ic8] bf16 ; taps 81..83 zeroed
#define WT_TAPS_P 84
#define WT_ELEMS  (WT_TAPS_P*2*OUT_C*8)      // 43,008 bf16 = 86,016 B

// conv LDS: A slab = 20 rows x 1088 B (18 valid + 2 pad -> 1280 lines), dbuf.
// B = 84 taps x 1024 B staged once. Total 2*20480 + 86016 = 126,976 B.
#define A_SLAB_B 20480
#define B_LDS_B  86016

typedef __bf16 bf16x8 __attribute__((ext_vector_type(8)));
typedef float  f32x4  __attribute__((ext_vector_type(4)));
typedef float  f32x16 __attribute__((ext_vector_type(16)));

__device__ __forceinline__ unsigned short f2bf(float f) {
    unsigned int u = __builtin_bit_cast(unsigned int, f);
    u += 0x7fffu + ((u >> 16) & 1u);       // RNE
    return (unsigned short)(u >> 16);
}

__device__ __forceinline__ void gload16(const void* g, void* l) {
    __builtin_amdgcn_global_load_lds(
        (const __attribute__((address_space(1))) unsigned int*)g,
        (__attribute__((address_space(3))) unsigned int*)l, 16, 0, 0);
}

// ---------------- fused prep: xpose rows + halo zeroing + weight xform ----------------
// blocks 0..4095   : one interior (n,t,d,h) row -> write full 1088B row (w-edges = 0)
// blocks 4096..6799: one halo row -> 68 x 16B zeros
// blocks 6800..6963: weight transform (164 x 256 = 43,008 elems exactly)
__global__ __launch_bounds__(256) void prep_kernel(const float* __restrict__ x,
                                                   const float* __restrict__ wsrc,
                                                   unsigned short* __restrict__ xt,
                                                   unsigned short* __restrict__ wt) {
    int b = blockIdx.x;
    int tid = threadIdx.x;
    if (b < 4096) {
        __shared__ unsigned short ls[WW * IN_C];   // [w][c], 1 KiB
        int h = b & 31, d = (b >> 5) & 7, t = (b >> 8) & 7, n = b >> 11;
        int c = tid >> 5, w = tid & 31;
        float v0 = x[((((size_t)(n * IN_C + c)     * TT + t) * DD + d) * HH + h) * WW + w];
        float v1 = x[((((size_t)(n * IN_C + c + 8) * TT + t) * DD + d) * HH + h) * WW + w];
        ls[w * 16 + c]     = f2bf(v0);
        ls[w * 16 + c + 8] = f2bf(v1);
        __syncthreads();
        if (tid < 68) {                 // line = blk*34 + wl
            int blk = tid / 34, wl = tid % 34;
            unsigned char* row = (unsigned char*)xt +
                (size_t)(((n * TP + t + 1) * DP + d + 1) * HP + h + 1) * XT_ROW_B;
            f32x4 val = {0.f, 0.f, 0.f, 0.f};
            if (wl != 0 && wl != 33)
                val = *(const f32x4*)((const unsigned char*)ls + (wl - 1) * 32 + blk * 16);
            *(f32x4*)(row + tid * 16) = val;
        }
    } else if (b < 6800) {
        int j = b - 4096;               // 2704 halo rows
        int n, tp, dp, hp;
        if (j < 1360)      { n = j / 680;  int r = j % 680;  tp = (r / 340) * 9; int r2 = r % 340; dp = r2 / 34;       hp = r2 % 34; }
        else if (j < 2448) { int j2 = j - 1360; n = j2 / 544; int r = j2 % 544; tp = 1 + r / 68;  int r3 = r % 68;  dp = (r3 / 34) * 9; hp = r3 % 34; }
        else               { int j3 = j - 2448; n = j3 / 128; int r = j3 % 128; tp = 1 + r / 16;  int r4 = r % 16;  dp = 1 + r4 / 2;   hp = (r4 & 1) * 33; }
        if (tid < 68) {
            unsigned char* row = (unsigned char*)xt +
                (size_t)(((n * TP + tp) * DP + dp) * HP + hp) * XT_ROW_B;
            f32x4 z = {0.f, 0.f, 0.f, 0.f};
            *(f32x4*)(row + tid * 16) = z;
        }
    } else {
        int idx = (b - 6800) * 256 + tid;   // 0..43007
        int tap = idx >> 9;
        int r = idx & 511;
        int icblk = r >> 8, oc = (r >> 3) & 31, i8 = r & 7;
        int ic = icblk * 8 + i8;
        float v = (tap < 81) ? wsrc[(oc * IN_C + ic) * 81 + tap] : 0.0f;
        wt[idx] = f2bf(v);
    }
}

// ---------------- main: 32x32x16 MFMA, producer/consumer wave specialization ----------
// block = 8 waves (512 thr): waves 0..3 compute (R5 structure: wave owns 4 h-rows,
// 36 MFMA + 27 ds_read_b128 per plane), waves 4..7 stage next A-plane.
// Every SIMD holds 1 consumer + 1 producer wave -> staging latency hides under MFMA.
__global__ __launch_bounds__(512, 1) void conv_main_kernel(const unsigned short* __restrict__ xt,
                                                           const unsigned short* __restrict__ wt,
                                                           const float* __restrict__ bias,
                                                           float* __restrict__ out) {
    __shared__ __align__(16) unsigned char As0[A_SLAB_B];
    __shared__ __align__(16) unsigned char As1[A_SLAB_B];
    __shared__ __align__(16) unsigned char Bs[B_LDS_B];

    // XCD-aware swizzle (256 blocks, 256 % 8 == 0 -> bijective)
    int bid = blockIdx.x;
    int lb  = (bid & 7) * 32 + (bid >> 3);
    int hb = lb & 1, d = (lb >> 1) & 7, t = (lb >> 4) & 7, n = lb >> 7;
    int h0 = hb * 16;                  // padded base row of slab
    int tid  = threadIdx.x;
    int wv   = tid >> 6;               // 0..3 consumers, 4..7 producers
    int lane = tid & 63;
    int l31  = lane & 31;
    int kblk = lane >> 5;

    int ab = kblk * 544 + l31 * 16;    // A-frag lane offset within a row
    int bb = kblk * 512 + l31 * 16;    // B-frag lane offset within a tap

    // ---- prologue: stage all B (5376 lines) + A plane 0 (1280 lines), all threads ----
#pragma unroll
    for (int i = 0; i < 10; ++i)
        gload16((const unsigned char*)wt + (tid + i * 512) * 16, Bs + (tid + i * 512) * 16);
    if (tid < 256)
        gload16((const unsigned char*)wt + (tid + 5120) * 16, Bs + (tid + 5120) * 16);
    {
        const unsigned char* src = (const unsigned char*)xt +
            (size_t)(((n * TP + t) * DP + d) * HP + h0) * XT_ROW_B;
        gload16(src + tid * 16,          As0 + tid * 16);
        gload16(src + (tid + 512) * 16,  As0 + (tid + 512) * 16);
        if (tid < 256)
            gload16(src + (tid + 1024) * 16, As0 + (tid + 1024) * 16);
    }
    asm volatile("s_waitcnt vmcnt(0)" ::: "memory");
    __syncthreads();

    f32x16 acc[4];
#pragma unroll
    for (int m = 0; m < 4; ++m) acc[m] = {};

    // ---- 9 phases: consumers compute plane p from buf[p&1];
    //      producers stage plane p+1 into buf[(p+1)&1] (disjoint) ----
#pragma unroll
    for (int p = 0; p < 9; ++p) {
        if (wv >= 4) {
            if (p < 8) {
                const int ktn = (p + 1) / 3, kdn = (p + 1) % 3;
                const unsigned char* src = (const unsigned char*)xt +
                    (size_t)(((n * TP + t + ktn) * DP + d + kdn) * HP + h0) * XT_ROW_B;
                unsigned char* dst = (p & 1) ? As0 : As1;
                int tid2 = tid - 256;
#pragma unroll
                for (int i = 0; i < 5; ++i)
                    gload16(src + (tid2 + i * 256) * 16, dst + (tid2 + i * 256) * 16);
                asm volatile("s_waitcnt vmcnt(0)" ::: "memory");
            }
        } else {
            const unsigned char* A = (p & 1) ? As1 : As0;
            const int kt = p / 3, kd = p % 3;

            bf16x8 bf[3][3];
#pragma unroll
            for (int kh = 0; kh < 3; ++kh)
#pragma unroll
                for (int kw = 0; kw < 3; ++kw)
                    bf[kh][kw] = *(const bf16x8*)(Bs + ((kt * 27 + kd * 9 + kh * 3 + kw) << 10) + bb);

#pragma unroll
            for (int r = 0; r < 6; ++r) {
#pragma unroll
                for (int kw = 0; kw < 3; ++kw) {
                    bf16x8 a = *(const bf16x8*)(A + (4 * wv + r) * 1088 + ab + kw * 16);
#pragma unroll
                    for (int kh = 0; kh < 3; ++kh) {
                        const int m = r - kh;
                        if (m >= 0 && m < 4)
                            acc[m] = __builtin_amdgcn_mfma_f32_32x32x16_bf16(a, bf[kh][kw], acc[m], 0, 0, 0);
                    }
                }
            }
        }
        __syncthreads();
    }

    // ---- epilogue (consumers): col(oc)=l31, row(w)=(reg&3)+8*(reg>>2)+4*kblk ----
    if (wv < 4) {
        float bsv = bias[l31];
#pragma unroll
        for (int m = 0; m < 4; ++m) {
            int oh = h0 + 4 * wv + m;
            float* obase = out + (((((size_t)n * OUT_C + l31) * TT + t) * DD + d) * HH + oh) * WW;
#pragma unroll
            for (int q = 0; q < 4; ++q) {
                f32x4 v = { acc[m][4 * q + 0] + bsv, acc[m][4 * q + 1] + bsv,
                            acc[m][4 * q + 2] + bsv, acc[m][4 * q + 3] + bsv };
                *(f32x4*)(obase + 8 * q + 4 * kblk) = v;
            }
        }
    }
}

extern "C" void kernel_launch(void* const* d_in, const int* in_sizes, int n_in,
                              void* d_out, int out_size, void* d_ws, size_t ws_size,
                              hipStream_t stream) {
    const float* x    = (const float*)d_in[0];
    const float* wsrc = (const float*)d_in[1];
    const float* bias = (const float*)d_in[2];
    float* out        = (float*)d_out;

    unsigned short* xt = (unsigned short*)d_ws;
    unsigned short* wt = xt + XT_ELEMS;

    prep_kernel<<<4096 + 2704 + 164, 256, 0, stream>>>(x, wsrc, xt, wt);
    conv_main_kernel<<<NB * TT * DD * 2, 512, 0, stream>>>(xt, wt, bias, out);
}